// Round 1
// baseline (235.537 us; speedup 1.0000x reference)
//
#include <hip/hip_runtime.h>
#include <hip/hip_bf16.h>
#include <math.h>

#define S_DIM 2048
#define B_DIM 64
#define H_DIM 1024

// ---------------------------------------------------------------------------
// Kernel 1: v[b,h] = sum_k hidden[b,k] * W[k,h];  c[b] = dot(hidden[b], bias)
// One block per b (64 blocks, 256 threads). Each thread owns 4 h-values.
// W row k is read as a full coalesced 4KB row per iteration.
// ---------------------------------------------------------------------------
__global__ __launch_bounds__(256) void v_kernel(
    const float* __restrict__ hidden,   // [B,H] (leading 1 dropped)
    const float* __restrict__ W,        // [H,H] row k, col h
    const float* __restrict__ bias,     // [H]
    float* __restrict__ v,              // [B,H]
    float* __restrict__ c)              // [B]
{
    const int b   = blockIdx.x;
    const int tid = threadIdx.x;
    const int h0  = tid * 4;
    const float* hb = hidden + (size_t)b * H_DIM;

    float4 acc = make_float4(0.f, 0.f, 0.f, 0.f);
#pragma unroll 4
    for (int k = 0; k < H_DIM; ++k) {
        const float hk = hb[k];  // wave-uniform -> scalar load
        const float4 w = *reinterpret_cast<const float4*>(W + (size_t)k * H_DIM + h0);
        acc.x = fmaf(hk, w.x, acc.x);
        acc.y = fmaf(hk, w.y, acc.y);
        acc.z = fmaf(hk, w.z, acc.z);
        acc.w = fmaf(hk, w.w, acc.w);
    }
    *reinterpret_cast<float4*>(v + (size_t)b * H_DIM + h0) = acc;

    // c[b] = dot(hidden[b], bias) via block reduction
    const float4 hv = *reinterpret_cast<const float4*>(hb + h0);
    const float4 bv = *reinterpret_cast<const float4*>(bias + h0);
    float part = hv.x * bv.x + hv.y * bv.y + hv.z * bv.z + hv.w * bv.w;

    __shared__ float red[256];
    red[tid] = part;
    __syncthreads();
    for (int off = 128; off > 0; off >>= 1) {
        if (tid < off) red[tid] += red[tid + off];
        __syncthreads();
    }
    if (tid == 0) c[b] = red[0];
}

// ---------------------------------------------------------------------------
// Kernel 2: scores[b,s] = dot(v[b,:], enc[s,b,:]) + c[b]
// Grid: (S/64, B). Block = 256 threads = 4 waves; each wave does 16 s-values.
// v fragment lives in registers (16 floats/lane), enc rows are contiguous
// 4KB chunks -> fully coalesced float4 loads.
// ---------------------------------------------------------------------------
__global__ __launch_bounds__(256) void scores_kernel(
    const float* __restrict__ enc,      // [S,B,H]
    const float* __restrict__ v,        // [B,H]
    const float* __restrict__ c,        // [B]
    float* __restrict__ scores)         // [B,S]
{
    const int b      = blockIdx.y;
    const int wave   = threadIdx.x >> 6;
    const int lane   = threadIdx.x & 63;
    const int s_base = blockIdx.x * 64 + wave * 16;

    const float* vb = v + (size_t)b * H_DIM;
    const int o = lane * 4;
    const float4 v0 = *reinterpret_cast<const float4*>(vb + o);
    const float4 v1 = *reinterpret_cast<const float4*>(vb + o + 256);
    const float4 v2 = *reinterpret_cast<const float4*>(vb + o + 512);
    const float4 v3 = *reinterpret_cast<const float4*>(vb + o + 768);
    const float cb = c[b];

#pragma unroll 2
    for (int i = 0; i < 16; ++i) {
        const int s = s_base + i;
        const float* e = enc + ((size_t)s * B_DIM + b) * H_DIM;
        const float4 e0 = *reinterpret_cast<const float4*>(e + o);
        const float4 e1 = *reinterpret_cast<const float4*>(e + o + 256);
        const float4 e2 = *reinterpret_cast<const float4*>(e + o + 512);
        const float4 e3 = *reinterpret_cast<const float4*>(e + o + 768);

        float acc = v0.x * e0.x + v0.y * e0.y + v0.z * e0.z + v0.w * e0.w
                  + v1.x * e1.x + v1.y * e1.y + v1.z * e1.z + v1.w * e1.w
                  + v2.x * e2.x + v2.y * e2.y + v2.z * e2.z + v2.w * e2.w
                  + v3.x * e3.x + v3.y * e3.y + v3.z * e3.z + v3.w * e3.w;

        // 64-lane butterfly reduce
#pragma unroll
        for (int off = 32; off > 0; off >>= 1)
            acc += __shfl_xor(acc, off);

        if (lane == 0) scores[(size_t)b * S_DIM + s] = acc + cb;
    }
}

// ---------------------------------------------------------------------------
// Kernel 3: out[b,0,s] = softmax over s of scores[b,:]
// One block (256 threads) per b; each thread owns 8 s-values.
// ---------------------------------------------------------------------------
__global__ __launch_bounds__(256) void softmax_kernel(
    const float* __restrict__ scores,   // [B,S]
    float* __restrict__ out)            // [B,1,S]
{
    const int b   = blockIdx.x;
    const int tid = threadIdx.x;
    const float* row = scores + (size_t)b * S_DIM;

    float vals[8];
    float m = -INFINITY;
#pragma unroll
    for (int i = 0; i < 8; ++i) {
        vals[i] = row[tid + i * 256];
        m = fmaxf(m, vals[i]);
    }

    __shared__ float red[256];
    red[tid] = m;
    __syncthreads();
    for (int off = 128; off > 0; off >>= 1) {
        if (tid < off) red[tid] = fmaxf(red[tid], red[tid + off]);
        __syncthreads();
    }
    m = red[0];
    __syncthreads();

    float sum = 0.f;
#pragma unroll
    for (int i = 0; i < 8; ++i) {
        vals[i] = __expf(vals[i] - m);
        sum += vals[i];
    }
    red[tid] = sum;
    __syncthreads();
    for (int off = 128; off > 0; off >>= 1) {
        if (tid < off) red[tid] += red[tid + off];
        __syncthreads();
    }
    const float inv = 1.0f / red[0];
    __syncthreads();

#pragma unroll
    for (int i = 0; i < 8; ++i)
        out[(size_t)b * S_DIM + tid + i * 256] = vals[i] * inv;
}

// ---------------------------------------------------------------------------
extern "C" void kernel_launch(void* const* d_in, const int* in_sizes, int n_in,
                              void* d_out, int out_size, void* d_ws, size_t ws_size,
                              hipStream_t stream) {
    const float* hidden = (const float*)d_in[0];   // [1,B,H]
    const float* enc    = (const float*)d_in[1];   // [S,B,H]
    const float* W      = (const float*)d_in[2];   // [H,H]
    const float* bias   = (const float*)d_in[3];   // [H]
    float* out          = (float*)d_out;           // [B,1,S]

    float* ws     = (float*)d_ws;
    float* v      = ws;                            // B*H floats   (256 KB)
    float* c      = ws + (size_t)B_DIM * H_DIM;    // B floats
    float* scores = c + B_DIM;                     // B*S floats   (512 KB)

    v_kernel<<<dim3(B_DIM), dim3(256), 0, stream>>>(hidden, W, bias, v, c);
    scores_kernel<<<dim3(S_DIM / 64, B_DIM), dim3(256), 0, stream>>>(enc, v, c, scores);
    softmax_kernel<<<dim3(B_DIM), dim3(256), 0, stream>>>(scores, out);
}

// Round 3
// 106.940 us; speedup vs baseline: 2.2025x; 2.2025x over previous
//
#include <hip/hip_runtime.h>
#include <hip/hip_bf16.h>
#include <math.h>

#define S_DIM 2048
#define B_DIM 64
#define H_DIM 1024
#define KP    8                    // k-split factor for the v GEMM
#define KCHUNK (H_DIM / KP)        // 128

typedef float f32x4 __attribute__((ext_vector_type(4)));

// ---------------------------------------------------------------------------
// Kernel 1a: partial[p,b,h] = sum_{k in chunk p} hidden[b,k] * W[k,h]
// Grid (B, KP) = 512 blocks x 256 threads -> 2048 waves (8x round-0
// parallelism, 8x shorter dependent-load chains). Each thread owns 4 h.
// ---------------------------------------------------------------------------
__global__ __launch_bounds__(256) void v_partial_kernel(
    const float* __restrict__ hidden,   // [B,H]
    const float* __restrict__ W,        // [H,H]
    float* __restrict__ partial)        // [KP,B,H]
{
    const int b   = blockIdx.x;
    const int p   = blockIdx.y;
    const int tid = threadIdx.x;
    const int h0  = tid * 4;
    const float* hb = hidden + (size_t)b * H_DIM;
    const int k0 = p * KCHUNK;

    f32x4 acc = (f32x4)0.f;
#pragma unroll 8
    for (int kk = 0; kk < KCHUNK; ++kk) {
        const int k = k0 + kk;
        const float hk = hb[k];
        const f32x4 w = *reinterpret_cast<const f32x4*>(W + (size_t)k * H_DIM + h0);
        acc.x = fmaf(hk, w.x, acc.x);
        acc.y = fmaf(hk, w.y, acc.y);
        acc.z = fmaf(hk, w.z, acc.z);
        acc.w = fmaf(hk, w.w, acc.w);
    }
    *reinterpret_cast<f32x4*>(partial + ((size_t)p * B_DIM + b) * H_DIM + h0) = acc;
}

// ---------------------------------------------------------------------------
// Kernel 1b: v[b,h] = sum_p partial[p,b,h];  c[b] = dot(hidden[b], bias)
// ---------------------------------------------------------------------------
__global__ __launch_bounds__(256) void v_reduce_kernel(
    const float* __restrict__ partial,  // [KP,B,H]
    const float* __restrict__ hidden,   // [B,H]
    const float* __restrict__ bias,     // [H]
    float* __restrict__ v,              // [B,H]
    float* __restrict__ c)              // [B]
{
    const int b   = blockIdx.x;
    const int tid = threadIdx.x;
    const int h0  = tid * 4;

    f32x4 s = (f32x4)0.f;
#pragma unroll
    for (int p = 0; p < KP; ++p) {
        const f32x4 t = *reinterpret_cast<const f32x4*>(
            partial + ((size_t)p * B_DIM + b) * H_DIM + h0);
        s += t;
    }
    *reinterpret_cast<f32x4*>(v + (size_t)b * H_DIM + h0) = s;

    const float* hb = hidden + (size_t)b * H_DIM;
    const f32x4 hv = *reinterpret_cast<const f32x4*>(hb + h0);
    const f32x4 bv = *reinterpret_cast<const f32x4*>(bias + h0);
    float part = hv.x * bv.x + hv.y * bv.y + hv.z * bv.z + hv.w * bv.w;

    __shared__ float red[256];
    red[tid] = part;
    __syncthreads();
    for (int off = 128; off > 0; off >>= 1) {
        if (tid < off) red[tid] += red[tid + off];
        __syncthreads();
    }
    if (tid == 0) c[b] = red[0];
}

// ---------------------------------------------------------------------------
// Kernel 2: scores[b,s] = dot(v[b,:], enc[s,b,:]) + c[b]
// Grid (S/64, B), 256 threads = 4 waves, 16 s per wave processed in pairs
// (independent accumulators -> 8 float4 loads in flight). enc is streamed
// with nontemporal loads (read-once; don't thrash L2).
// ---------------------------------------------------------------------------
__global__ __launch_bounds__(256) void scores_kernel(
    const float* __restrict__ enc,      // [S,B,H]
    const float* __restrict__ v,        // [B,H]
    const float* __restrict__ c,        // [B]
    float* __restrict__ scores)         // [B,S]
{
    const int b      = blockIdx.y;
    const int wave   = threadIdx.x >> 6;
    const int lane   = threadIdx.x & 63;
    const int s_base = blockIdx.x * 64 + wave * 16;

    const float* vb = v + (size_t)b * H_DIM;
    const int o = lane * 4;
    const f32x4 v0 = *reinterpret_cast<const f32x4*>(vb + o);
    const f32x4 v1 = *reinterpret_cast<const f32x4*>(vb + o + 256);
    const f32x4 v2 = *reinterpret_cast<const f32x4*>(vb + o + 512);
    const f32x4 v3 = *reinterpret_cast<const f32x4*>(vb + o + 768);
    const float cb = c[b];

#pragma unroll 2
    for (int i = 0; i < 16; i += 2) {
        const float* ea = enc + ((size_t)(s_base + i) * B_DIM + b) * H_DIM;
        const float* eb = ea + (size_t)B_DIM * H_DIM;   // next s row

        const f32x4 a0 = __builtin_nontemporal_load(reinterpret_cast<const f32x4*>(ea + o));
        const f32x4 a1 = __builtin_nontemporal_load(reinterpret_cast<const f32x4*>(ea + o + 256));
        const f32x4 a2 = __builtin_nontemporal_load(reinterpret_cast<const f32x4*>(ea + o + 512));
        const f32x4 a3 = __builtin_nontemporal_load(reinterpret_cast<const f32x4*>(ea + o + 768));
        const f32x4 b0 = __builtin_nontemporal_load(reinterpret_cast<const f32x4*>(eb + o));
        const f32x4 b1 = __builtin_nontemporal_load(reinterpret_cast<const f32x4*>(eb + o + 256));
        const f32x4 b2 = __builtin_nontemporal_load(reinterpret_cast<const f32x4*>(eb + o + 512));
        const f32x4 b3 = __builtin_nontemporal_load(reinterpret_cast<const f32x4*>(eb + o + 768));

        float acc_a = v0.x * a0.x + v0.y * a0.y + v0.z * a0.z + v0.w * a0.w
                    + v1.x * a1.x + v1.y * a1.y + v1.z * a1.z + v1.w * a1.w
                    + v2.x * a2.x + v2.y * a2.y + v2.z * a2.z + v2.w * a2.w
                    + v3.x * a3.x + v3.y * a3.y + v3.z * a3.z + v3.w * a3.w;
        float acc_b = v0.x * b0.x + v0.y * b0.y + v0.z * b0.z + v0.w * b0.w
                    + v1.x * b1.x + v1.y * b1.y + v1.z * b1.z + v1.w * b1.w
                    + v2.x * b2.x + v2.y * b2.y + v2.z * b2.z + v2.w * b2.w
                    + v3.x * b3.x + v3.y * b3.y + v3.z * b3.z + v3.w * b3.w;

#pragma unroll
        for (int off = 32; off > 0; off >>= 1) {
            acc_a += __shfl_xor(acc_a, off);
            acc_b += __shfl_xor(acc_b, off);
        }

        if (lane == 0) {
            scores[(size_t)b * S_DIM + s_base + i]     = acc_a + cb;
            scores[(size_t)b * S_DIM + s_base + i + 1] = acc_b + cb;
        }
    }
}

// ---------------------------------------------------------------------------
// Kernel 3: out[b,0,s] = softmax over s of scores[b,:]
// ---------------------------------------------------------------------------
__global__ __launch_bounds__(256) void softmax_kernel(
    const float* __restrict__ scores,   // [B,S]
    float* __restrict__ out)            // [B,1,S]
{
    const int b   = blockIdx.x;
    const int tid = threadIdx.x;
    const float* row = scores + (size_t)b * S_DIM;

    float vals[8];
    float m = -INFINITY;
#pragma unroll
    for (int i = 0; i < 8; ++i) {
        vals[i] = row[tid + i * 256];
        m = fmaxf(m, vals[i]);
    }

    __shared__ float red[256];
    red[tid] = m;
    __syncthreads();
    for (int off = 128; off > 0; off >>= 1) {
        if (tid < off) red[tid] = fmaxf(red[tid], red[tid + off]);
        __syncthreads();
    }
    m = red[0];
    __syncthreads();

    float sum = 0.f;
#pragma unroll
    for (int i = 0; i < 8; ++i) {
        vals[i] = __expf(vals[i] - m);
        sum += vals[i];
    }
    red[tid] = sum;
    __syncthreads();
    for (int off = 128; off > 0; off >>= 1) {
        if (tid < off) red[tid] += red[tid + off];
        __syncthreads();
    }
    const float inv = 1.0f / red[0];
    __syncthreads();

#pragma unroll
    for (int i = 0; i < 8; ++i)
        out[(size_t)b * S_DIM + tid + i * 256] = vals[i] * inv;
}

// ---------------------------------------------------------------------------
extern "C" void kernel_launch(void* const* d_in, const int* in_sizes, int n_in,
                              void* d_out, int out_size, void* d_ws, size_t ws_size,
                              hipStream_t stream) {
    const float* hidden = (const float*)d_in[0];   // [1,B,H]
    const float* enc    = (const float*)d_in[1];   // [S,B,H]
    const float* W      = (const float*)d_in[2];   // [H,H]
    const float* bias   = (const float*)d_in[3];   // [H]
    float* out          = (float*)d_out;           // [B,1,S]

    float* ws      = (float*)d_ws;
    float* partial = ws;                                       // KP*B*H (2 MB)
    float* v       = partial + (size_t)KP * B_DIM * H_DIM;     // B*H (256 KB)
    float* c       = v + (size_t)B_DIM * H_DIM;                // B
    float* scores  = c + B_DIM;                                // B*S (512 KB)

    v_partial_kernel<<<dim3(B_DIM, KP), dim3(256), 0, stream>>>(hidden, W, partial);
    v_reduce_kernel<<<dim3(B_DIM), dim3(256), 0, stream>>>(partial, hidden, bias, v, c);
    scores_kernel<<<dim3(S_DIM / 64, B_DIM), dim3(256), 0, stream>>>(enc, v, c, scores);
    softmax_kernel<<<dim3(B_DIM), dim3(256), 0, stream>>>(scores, out);
}